// Round 18
// baseline (278.808 us; speedup 1.0000x reference)
//
#include <hip/hip_runtime.h>
#include <math.h>

#define N_NODES 20000
#define E_EDGES 200000
#define K1_KEEP 10000
#define K2_KEEP 5000
#define HIDC 128
#define NHEAD 4
#define FDIM 512   // NHEAD*HIDC
#define NEG 0.2f
#define BSTRIDE 64 // bucket CSR stride
#define MPAD 10112  // 79*128: K1 rows padded to GEMM2 tile grid
#define MPAD1 20096 // 157*128: N rows padded to GEMM1 tile grid
#define FR_GRID 250 // final_reduce blocks: 250*40 == K1_KEEP
#define FR_RPB 40   // rows per block (contiguous stream)
#define SELWORDS 8512  // per-pool select buffers: 4096+4096+256+64 dwords

typedef _Float16 half8 __attribute__((ext_vector_type(8)));
typedef _Float16 half4 __attribute__((ext_vector_type(4)));
typedef float f32x4 __attribute__((ext_vector_type(4)));

__device__ __forceinline__ float leaky(float x){ return x > 0.f ? x : NEG * x; }
__device__ __forceinline__ float elu(float x){ return x > 0.f ? x : expm1f(x); }
// monotone float->uint key (ascending)
__device__ __forceinline__ unsigned ordkey(float f){
    unsigned u = __float_as_uint(f);
    return (u & 0x80000000u) ? ~u : (u | 0x80000000u);
}

// ---- prep_all: prep_x + W1 split + tmp zero + pw1-norm + W2 split + selbuf zero
__global__ __launch_bounds__(256) void prep_all(const float* __restrict__ x,
        _Float16* __restrict__ X0, _Float16* __restrict__ X1,
        const float* __restrict__ W1, _Float16* __restrict__ B10, _Float16* __restrict__ B11,
        const float* __restrict__ W2, _Float16* __restrict__ B20, _Float16* __restrict__ B21,
        int* __restrict__ ctmp, int cn,
        const float* __restrict__ cw, float* __restrict__ cinvn,
        unsigned* __restrict__ selbuf)
{
    int bid = blockIdx.x;
    int t = threadIdx.x;
    if (bid < 628){                       // --- prep_x: MPAD1*8 threads ---
        int tid = bid * 256 + t;
        int r = tid >> 3, c8 = (tid & 7) << 3;
        half8 v0 = (half8)0, v1 = (half8)0;
        if (r < N_NODES){
            const float4* p = reinterpret_cast<const float4*>(&x[(size_t)r * 64 + c8]);
            float4 x0 = p[0], x1 = p[1];
            float vals[8] = {x0.x, x0.y, x0.z, x0.w, x1.x, x1.y, x1.z, x1.w};
#pragma unroll
            for (int j = 0; j < 8; ++j){
                _Float16 h = (_Float16)vals[j];
                v0[j] = h;
                v1[j] = (_Float16)(vals[j] - (float)h);
            }
        }
        if (r < MPAD1){
            *reinterpret_cast<half8*>(&X0[(size_t)r * 64 + c8]) = v0;
            *reinterpret_cast<half8*>(&X1[(size_t)r * 64 + c8]) = v1;
        }
    } else if (bid < 660){                // --- W1[64][512] transpose-split ---
        __shared__ float tile[32][33];
        int b = bid - 628;
        int bn = b & 15, bk = b >> 4;
        int n0 = bn * 32, k0 = bk * 32;
        int j = t & 31, i0 = t >> 5;
#pragma unroll
        for (int ii = 0; ii < 32; ii += 8)
            tile[i0 + ii][j] = W1[(size_t)(k0 + i0 + ii) * 512 + n0 + j];
        __syncthreads();
#pragma unroll
        for (int ii = 0; ii < 32; ii += 8){
            float v = tile[j][i0 + ii];   // = W1[k0+j][n0+i0+ii]
            _Float16 h0 = (_Float16)v;
            _Float16 h1 = (_Float16)(v - (float)h0);
            size_t o = (size_t)(n0 + i0 + ii) * 64 + k0 + j;
            B10[o] = h0; B11[o] = h1;
        }
    } else if (bid < 739){                // --- tmp zero (degree counters) ---
        int i = (bid - 660) * 256 + t;
        if (i < cn) ctmp[i] = 0;
    } else if (bid == 739){               // --- 1/||pw1|| ---
        __shared__ float redc[4];
        float s = cw[t] * cw[t] + cw[t + 256] * cw[t + 256];
#pragma unroll
        for (int off = 32; off > 0; off >>= 1) s += __shfl_xor(s, off);
        if ((t & 63) == 0) redc[t >> 6] = s;
        __syncthreads();
        if (t == 0) *cinvn = rsqrtf(redc[0] + redc[1] + redc[2] + redc[3]);
    } else if (bid < 996){                // --- W2[512][512] transpose-split ---
        __shared__ float tile[32][33];
        int b = bid - 740;
        int bn = b & 15, bk = b >> 4;
        int n0 = bn * 32, k0 = bk * 32;
        int j = t & 31, i0 = t >> 5;
#pragma unroll
        for (int ii = 0; ii < 32; ii += 8)
            tile[i0 + ii][j] = W2[(size_t)(k0 + i0 + ii) * 512 + n0 + j];
        __syncthreads();
#pragma unroll
        for (int ii = 0; ii < 32; ii += 8){
            float v = tile[j][i0 + ii];   // = W2[k0+j][n0+i0+ii]
            _Float16 h0 = (_Float16)v;
            _Float16 h1 = (_Float16)(v - (float)h0);
            size_t o = (size_t)(n0 + i0 + ii) * 512 + k0 + j;
            B20[o] = h0; B21[o] = h1;
        }
    } else {                              // --- select buffers zero (2 pools) ---
        int i = (bid - 996) * 256 + t;
        if (i < 2 * SELWORDS) selbuf[i] = 0u;
    }
}

// --------- prep: scatter gather+scale+fp16x2-split A -> planes [MPAD][512] -
// r17-verified: iterates ORIGINAL nodes o, writes row remap[o].
__global__ __launch_bounds__(256) void prep_a2(const float* __restrict__ out1,
        const int* __restrict__ remap, const float* __restrict__ score,
        _Float16* __restrict__ A0, _Float16* __restrict__ A1)
{
    int tid = blockIdx.x * 256 + threadIdx.x;
    int o = tid >> 6, kq = (tid & 63) << 3;
    if (o < N_NODES){
        int r = remap[o];
        if (r < 0) return;
        float sc = score[o];
        const float4* p = reinterpret_cast<const float4*>(&out1[(size_t)o * 512 + kq]);
        float4 x0 = p[0], x1 = p[1];
        float vals[8] = {x0.x, x0.y, x0.z, x0.w, x1.x, x1.y, x1.z, x1.w};
        half8 v0, v1;
#pragma unroll
        for (int j = 0; j < 8; ++j){
            float v = vals[j] * sc;
            _Float16 h = (_Float16)v;
            v0[j] = h;
            v1[j] = (_Float16)(v - (float)h);
        }
        *reinterpret_cast<half8*>(&A0[(size_t)r * 512 + kq]) = v0;
        *reinterpret_cast<half8*>(&A1[(size_t)r * 512 + kq]) = v1;
    } else {
        int r = K1_KEEP + (o - N_NODES);        // pad rows K1..MPAD
        if (r < MPAD){
            *reinterpret_cast<half8*>(&A0[(size_t)r * 512 + kq]) = (half8)0;
            *reinterpret_cast<half8*>(&A1[(size_t)r * 512 + kq]) = (half8)0;
        }
    }
}

// ---------------- GEMM: fp16x2 split MFMA, 128x128 tile, templated K -------
template<int KK>
__global__ __launch_bounds__(256, 2) void gemm_mfma(
        const _Float16* __restrict__ A0, const _Float16* __restrict__ A1,
        const _Float16* __restrict__ B0, const _Float16* __restrict__ B1,
        const float* __restrict__ avS, const float* __restrict__ avD,
        _Float16* __restrict__ C, float* __restrict__ asrc, float* __restrict__ adst,
        int nrows)
{
    __shared__ _Float16 smem[2][4][128][32];   // 65536 B
    int t = threadIdx.x;
    int l = t & 63, w = t >> 6;
    int wr = w >> 1, wc = w & 1;
    int bidn = blockIdx.x & 3, bidm = blockIdx.x >> 2;
    int row0 = bidm * 128, col0 = bidn * 128;

    const _Float16* plane = (w == 0) ? A0 : (w == 1) ? A1 : (w == 2) ? B0 : B1;
    int prow0 = (w < 2) ? row0 : col0;
    int mloc = l >> 2;
    int gsw = (l & 3) ^ (mloc & 3);
    const _Float16* gbase = plane + (size_t)(prow0 + mloc) * KK + gsw * 8;

    f32x4 acc[4][4];
#pragma unroll
    for (int m = 0; m < 4; ++m)
#pragma unroll
        for (int n = 0; n < 4; ++n) acc[m][n] = (f32x4){0.f, 0.f, 0.f, 0.f};

    auto stage = [&](int buf, int chunk){
        const _Float16* src = gbase + chunk * 32;
        char* db = (char*)&smem[buf][w][0][0];
#pragma unroll
        for (int i = 0; i < 8; ++i)
            __builtin_amdgcn_global_load_lds(
                (const __attribute__((address_space(1))) void*)(src + (size_t)i * (KK * 16)),
                (__attribute__((address_space(3))) void*)(db + i * 1024), 16, 0, 0);
    };

    int rb = (l & 15) * 64 + (((l >> 4) ^ (l & 3)) * 16);
    const char* sb = (const char*)smem;

    constexpr int NCH = KK / 32;
    stage(0, 0);
    __syncthreads();
    for (int c = 0; c < NCH; ++c){
        int buf = c & 1;
        if (c < NCH - 1) stage(buf ^ 1, c + 1);
        const char* base = sb + buf * 32768;
        half8 a0[4], a1[4], b0[4], b1[4];
#pragma unroll
        for (int m = 0; m < 4; ++m){
            a0[m] = *(const half8*)(base +         wr * 4096 + m * 1024 + rb);
            a1[m] = *(const half8*)(base +  8192 + wr * 4096 + m * 1024 + rb);
            b0[m] = *(const half8*)(base + 16384 + wc * 4096 + m * 1024 + rb);
            b1[m] = *(const half8*)(base + 24576 + wc * 4096 + m * 1024 + rb);
        }
#pragma unroll
        for (int m = 0; m < 4; ++m)
#pragma unroll
            for (int n = 0; n < 4; ++n)
                acc[m][n] = __builtin_amdgcn_mfma_f32_16x16x32_f16(a0[m], b0[n], acc[m][n], 0, 0, 0);
#pragma unroll
        for (int m = 0; m < 4; ++m)
#pragma unroll
            for (int n = 0; n < 4; ++n)
                acc[m][n] = __builtin_amdgcn_mfma_f32_16x16x32_f16(a0[m], b1[n], acc[m][n], 0, 0, 0);
#pragma unroll
        for (int m = 0; m < 4; ++m)
#pragma unroll
            for (int n = 0; n < 4; ++n)
                acc[m][n] = __builtin_amdgcn_mfma_f32_16x16x32_f16(a1[m], b0[n], acc[m][n], 0, 0, 0);
        __syncthreads();
    }

    int head = bidn;
    const float* asv = avS + head * HIDC + wc * 64;
    const float* adv = avD + head * HIDC + wc * 64;
    int lc = l & 15, lg = l >> 4;
    int rbase = row0 + wr * 64;
    int cbase = col0 + wc * 64;
#pragma unroll
    for (int m = 0; m < 4; ++m){
#pragma unroll
        for (int q = 0; q < 4; ++q){
            int row = rbase + m * 16 + lg * 4 + q;
            bool ok = row < nrows;
            float s = 0.f, d = 0.f;
#pragma unroll
            for (int n = 0; n < 4; ++n){
                float v = acc[m][n][q];
                int cc = n * 16 + lc;
                if (ok) C[(size_t)row * 512 + cbase + cc] = (_Float16)v;
                s += v * asv[cc];
                d += v * adv[cc];
            }
#pragma unroll
            for (int off = 1; off < 16; off <<= 1){
                s += __shfl_xor(s, off);
                d += __shfl_xor(d, off);
            }
            if (ok && lc == 0){
                asrc[row * 8 + head * 2 + wc] = s;
                adst[row * 8 + head * 2 + wc] = d;
            }
        }
    }
}

// bucketed CSR fill
__global__ void edge_fill(const int* __restrict__ src, const int* __restrict__ dst, int e,
                          int* __restrict__ tmp, int* __restrict__ csr){
    int i = blockIdx.x * 256 + threadIdx.x;
    if (i >= e) return;
    int d = dst[i];
    int pos = atomicAdd(&tmp[d], 1);
    if (pos < BSTRIDE) csr[d * BSTRIDE + pos] = src[i];
}

// ---- fused softmax-stats + aggregation + pool score, one wave per node -----
template<bool FILTER>
__global__ __launch_bounds__(256) void gat_fused(const _Float16* __restrict__ h,
        const float* __restrict__ asrc, const float* __restrict__ adst,
        const int* __restrict__ degs, const int* __restrict__ csr,
        const int* __restrict__ remap,
        const float* __restrict__ bias, const float* __restrict__ pw,
        const float* __restrict__ invn, float* __restrict__ out,
        float* __restrict__ score, int n)
{
    int o = blockIdx.x * 4 + (threadIdx.x >> 6);
    int lane = threadIdx.x & 63;
    if (o >= n) return;
    int node, od;
    if (FILTER){
        node = remap[o];
        if (node < 0) return;
        od = o;
    } else {
        node = o; od = o;
    }
    int deg = degs[od]; if (deg > BSTRIDE) deg = BSTRIDE;
    int e0 = od * BSTRIDE;
    int ph = lane & 3;
    int pe = lane >> 2;
    float adn, sown;
    {
        float2 dv = *reinterpret_cast<const float2*>(&adst[(size_t)node * 8 + ph * 2]);
        float2 sv = *reinterpret_cast<const float2*>(&asrc[(size_t)node * 8 + ph * 2]);
        adn = dv.x + dv.y; sown = sv.x + sv.y;
    }
    float slog = leaky(sown + adn);
    int sreg[4];
    float mx = slog;
#pragma unroll
    for (int blk = 0; blk < 4; ++blk){
        int j = blk * 16 + pe;
        int s = -1;
        if (j < deg){
            s = csr[e0 + j];
            if (FILTER) s = remap[s];
            if (s >= 0){
                float2 v = *reinterpret_cast<const float2*>(&asrc[(size_t)s * 8 + ph * 2]);
                mx = fmaxf(mx, leaky(v.x + v.y + adn));
            }
        }
        sreg[blk] = s;
    }
#pragma unroll
    for (int off = 4; off < 64; off <<= 1) mx = fmaxf(mx, __shfl_xor(mx, off));
    float aexp[4];
    float lsum = 0.f;
#pragma unroll
    for (int blk = 0; blk < 4; ++blk){
        float ex = 0.f;
        int s = sreg[blk];
        if (s >= 0){
            float2 v = *reinterpret_cast<const float2*>(&asrc[(size_t)s * 8 + ph * 2]);
            ex = expf(leaky(v.x + v.y + adn) - mx);
        }
        aexp[blk] = ex;
        lsum += ex;
    }
#pragma unroll
    for (int off = 4; off < 64; off <<= 1) lsum += __shfl_xor(lsum, off);
    float es  = expf(slog - mx);
    float inv = 1.f / (lsum + es);

    int f0 = lane * 8;
    int hf = lane >> 4;
    float invh  = __shfl(inv, hf);
    float aself = __shfl(es, hf) * invh;
    float4 acc0, acc1;
    {
        half8 v = *reinterpret_cast<const half8*>(&h[(size_t)node * FDIM + f0]);
        acc0 = make_float4(aself * (float)v[0], aself * (float)v[1],
                           aself * (float)v[2], aself * (float)v[3]);
        acc1 = make_float4(aself * (float)v[4], aself * (float)v[5],
                           aself * (float)v[6], aself * (float)v[7]);
    }
#pragma unroll
    for (int blk = 0; blk < 4; ++blk){
        int base = blk * 16;
        if (base >= deg) break;
        int cnt = deg - base; if (cnt > 16) cnt = 16;
        for (int e = 0; e < cnt; ++e){
            int s = __shfl(sreg[blk], e * 4);
            if (FILTER && s < 0) continue;
            float al = __shfl(aexp[blk], e * 4 + hf) * invh;
            half8 u = *reinterpret_cast<const half8*>(&h[(size_t)s * FDIM + f0]);
            acc0.x += al * (float)u[0]; acc0.y += al * (float)u[1];
            acc0.z += al * (float)u[2]; acc0.w += al * (float)u[3];
            acc1.x += al * (float)u[4]; acc1.y += al * (float)u[5];
            acc1.z += al * (float)u[6]; acc1.w += al * (float)u[7];
        }
    }
    const float4* bp = reinterpret_cast<const float4*>(&bias[f0]);
    float4 b0 = bp[0], b1 = bp[1];
    float4 o0 = make_float4(elu(acc0.x + b0.x), elu(acc0.y + b0.y),
                            elu(acc0.z + b0.z), elu(acc0.w + b0.w));
    float4 o1 = make_float4(elu(acc1.x + b1.x), elu(acc1.y + b1.y),
                            elu(acc1.z + b1.z), elu(acc1.w + b1.w));
    float4* op = reinterpret_cast<float4*>(&out[(size_t)node * FDIM + f0]);
    op[0] = o0; op[1] = o1;
    const float4* wp = reinterpret_cast<const float4*>(&pw[f0]);
    float4 w0 = wp[0], w1 = wp[1];
    float s = o0.x * w0.x + o0.y * w0.y + o0.z * w0.z + o0.w * w0.w
            + o1.x * w1.x + o1.y * w1.y + o1.z * w1.z + o1.w * w1.w;
#pragma unroll
    for (int off = 32; off > 0; off >>= 1) s += __shfl_xor(s, off);
    if (lane == 0) score[node] = tanhf(s * (*invn));
}

// ==== r18: 3-barrier multi-block exact top-k select =========================
// Five single-CU theories failed (r11/r12/r16/r17: duration pinned ~48-50us);
// r13 multi-launch hit per-kernel latency floors; r14's 8 barriers cost too
// much. This keeps the multi-block structure with the MINIMUM 3 barriers
// (one per radix digit 12/12/8). Keys in 2 regs/thread. Per pass: LDS
// 4096-bin hist (pre-aggregation kills hot-bin global contention: <=nb
// RMWs/bin) -> flush nonzero bins to a DEDICATED pre-zeroed global buffer
// (no in-kernel re-zeroing) -> gbar -> EVERY block redundantly scans (16
// aloads/thread; deterministic, no broadcast round-trip). Compact = r14's
// verified block-scan + global base counters (no barrier).
// meta: [16]=gt_ctr [32]=tie_ctr [48]=bar_ctr [56]=bar_gen (pre-zeroed).
__global__ __launch_bounds__(256) void select3(const float* __restrict__ score,
        int n, int k, int nb, int* __restrict__ remap,
        unsigned* __restrict__ bA, unsigned* __restrict__ bB, unsigned* __restrict__ bC,
        unsigned* __restrict__ meta,
        float* __restrict__ zbuf, int zn,
        const float* __restrict__ w, float* __restrict__ invn)
{
    __shared__ unsigned hb[4096];
    __shared__ unsigned wt[4];
    __shared__ unsigned sPref, sR;
    __shared__ unsigned gbaseS, tbaseS;
    __shared__ float red2[4];
    int t = threadIdx.x, lane = t & 63, wv = t >> 6;
    int bid = blockIdx.x;
    int i0 = bid * 512 + t, i1 = i0 + 256;
    bool v0 = i0 < n, v1 = i1 < n;
    unsigned key0 = v0 ? ordkey(score[i0]) : 0u;
    unsigned key1 = v1 ? ordkey(score[i1]) : 0u;

    auto gbar = [&](){
        __syncthreads();
        if (t == 0){
            __threadfence();
            unsigned g = __hip_atomic_load(&meta[56], __ATOMIC_RELAXED,
                                           __HIP_MEMORY_SCOPE_AGENT);
            if (__hip_atomic_fetch_add(&meta[48], 1u, __ATOMIC_ACQ_REL,
                                       __HIP_MEMORY_SCOPE_AGENT) == (unsigned)(nb - 1)){
                __hip_atomic_store(&meta[48], 0u, __ATOMIC_RELAXED,
                                   __HIP_MEMORY_SCOPE_AGENT);
                __hip_atomic_store(&meta[56], g + 1u, __ATOMIC_RELEASE,
                                   __HIP_MEMORY_SCOPE_AGENT);
            } else {
                while (__hip_atomic_load(&meta[56], __ATOMIC_ACQUIRE,
                                         __HIP_MEMORY_SCOPE_AGENT) == g)
                    __builtin_amdgcn_s_sleep(1);
            }
            __threadfence();
        }
        __syncthreads();
    };

    // ===== pass A: bits[31:20] =====
    for (int i = t; i < 4096; i += 256) hb[i] = 0u;
    __syncthreads();
    if (v0) atomicAdd(&hb[key0 >> 20], 1u);
    if (v1) atomicAdd(&hb[key1 >> 20], 1u);
    __syncthreads();
    for (int i = t; i < 4096; i += 256){
        unsigned c = hb[i];
        if (c) atomicAdd(&bA[i], c);
    }
    gbar();
    {
        unsigned rem = (unsigned)k;
        unsigned c[16]; unsigned csum = 0;
#pragma unroll
        for (int j = 0; j < 16; ++j){
            c[j] = __hip_atomic_load(&bA[t * 16 + j], __ATOMIC_RELAXED,
                                     __HIP_MEMORY_SCOPE_AGENT);
            csum += c[j];
        }
        unsigned v = csum;
#pragma unroll
        for (int off = 1; off < 64; off <<= 1){
            unsigned o = __shfl_down(v, off);
            if (lane + off < 64) v += o;
        }
        if (lane == 0) wt[wv] = v;
        __syncthreads();
        unsigned hi = 0;
        for (int q = wv + 1; q < 4; ++q) hi += wt[q];
        unsigned run = v + hi - csum;      // suffix strictly after my chunk
#pragma unroll
        for (int j = 15; j >= 0; --j){
            unsigned suf = run + c[j];
            if (suf >= rem && run < rem){
                sPref = (unsigned)(t * 16 + j) << 20;
                sR = rem - run;
            }
            run = suf;
        }
    }
    __syncthreads();
    unsigned prefA = sPref, remA = sR;
    __syncthreads();

    // ===== pass B: bits[19:8] among prefix-A matches =====
    for (int i = t; i < 4096; i += 256) hb[i] = 0u;
    __syncthreads();
    if (v0 && (key0 >> 20) == (prefA >> 20)) atomicAdd(&hb[(key0 >> 8) & 0xFFFu], 1u);
    if (v1 && (key1 >> 20) == (prefA >> 20)) atomicAdd(&hb[(key1 >> 8) & 0xFFFu], 1u);
    __syncthreads();
    for (int i = t; i < 4096; i += 256){
        unsigned c = hb[i];
        if (c) atomicAdd(&bB[i], c);
    }
    gbar();
    {
        unsigned rem = remA;
        unsigned c[16]; unsigned csum = 0;
#pragma unroll
        for (int j = 0; j < 16; ++j){
            c[j] = __hip_atomic_load(&bB[t * 16 + j], __ATOMIC_RELAXED,
                                     __HIP_MEMORY_SCOPE_AGENT);
            csum += c[j];
        }
        unsigned v = csum;
#pragma unroll
        for (int off = 1; off < 64; off <<= 1){
            unsigned o = __shfl_down(v, off);
            if (lane + off < 64) v += o;
        }
        if (lane == 0) wt[wv] = v;
        __syncthreads();
        unsigned hi = 0;
        for (int q = wv + 1; q < 4; ++q) hi += wt[q];
        unsigned run = v + hi - csum;
#pragma unroll
        for (int j = 15; j >= 0; --j){
            unsigned suf = run + c[j];
            if (suf >= rem && run < rem){
                sPref = prefA | ((unsigned)(t * 16 + j) << 8);
                sR = rem - run;
            }
            run = suf;
        }
    }
    __syncthreads();
    unsigned prefB = sPref, remB = sR;
    __syncthreads();

    // ===== pass C: bits[7:0] among prefix-AB matches =====
    for (int i = t; i < 256; i += 256) hb[i] = 0u;   // t<256 -> hb[t]
    __syncthreads();
    if (v0 && (key0 >> 8) == (prefB >> 8)) atomicAdd(&hb[key0 & 255u], 1u);
    if (v1 && (key1 >> 8) == (prefB >> 8)) atomicAdd(&hb[key1 & 255u], 1u);
    __syncthreads();
    {
        unsigned c = hb[t];
        if (c) atomicAdd(&bC[t], c);
    }
    gbar();
    {
        unsigned rem = remB;
        unsigned cC = __hip_atomic_load(&bC[t], __ATOMIC_RELAXED,
                                        __HIP_MEMORY_SCOPE_AGENT);
        unsigned vC = cC;
#pragma unroll
        for (int off = 1; off < 64; off <<= 1){
            unsigned o = __shfl_down(vC, off);
            if (lane + off < 64) vC += o;
        }
        if (lane == 0) wt[wv] = vC;
        __syncthreads();
        unsigned hi = 0;
        for (int q = wv + 1; q < 4; ++q) hi += wt[q];
        vC += hi;
        unsigned nxt = vC - cC;
        if (vC >= rem && nxt < rem){
            sPref = prefB | (unsigned)t;
            sR = rem - nxt;
        }
    }
    __syncthreads();
    unsigned T = sPref, ties = sR;

    // ===== compact: r14-verified block-scan + global base counters =====
    int g0 = (v0 && key0 > T) ? 1 : 0, e0 = (v0 && key0 == T) ? 1 : 0;
    int g1 = (v1 && key1 > T) ? 1 : 0, e1 = (v1 && key1 == T) ? 1 : 0;
    unsigned pk = ((unsigned)(g0 + g1) << 16) | (unsigned)(e0 + e1);
    unsigned v = pk;
#pragma unroll
    for (int off = 1; off < 64; off <<= 1){
        unsigned o = __shfl_up(v, off);
        if (lane >= off) v += o;
    }
    if (lane == 63) wt[wv] = v;
    __syncthreads();
    unsigned wb = 0;
    for (int q = 0; q < wv; ++q) wb += wt[q];
    unsigned excl = wb + v - pk;
    if (t == 255){
        unsigned tot = wb + v;
        gbaseS = atomicAdd(&meta[16], tot >> 16);
        tbaseS = atomicAdd(&meta[32], tot & 0xFFFFu);
    }
    __syncthreads();
    int gpos = (int)(gbaseS + (excl >> 16));
    int tpos = (int)(tbaseS + (excl & 0xFFFFu));
    int gtot = k - (int)ties;
    if (v0){
        int pos = -1;
        if (g0) pos = gpos;
        else if (e0 && tpos < (int)ties) pos = gtot + tpos;
        remap[i0] = pos;
    }
    gpos += g0; tpos += e0;
    if (v1){
        int pos = -1;
        if (g1) pos = gpos;
        else if (e1 && tpos < (int)ties) pos = gtot + tpos;
        remap[i1] = pos;
    }
    if (bid == 0){
        if (w){
            float s = w[t] * w[t] + w[t + 256] * w[t + 256];
#pragma unroll
            for (int off = 32; off > 0; off >>= 1) s += __shfl_xor(s, off);
            if (lane == 0) red2[wv] = s;
            __syncthreads();
            if (t == 0) *invn = rsqrtf(red2[0] + red2[1] + red2[2] + red2[3]);
        }
        if (zbuf){
            if (t < zn) zbuf[t] = 0.f;
            if (t + 256 < zn) zbuf[t + 256] = 0.f;
        }
    }
}

// --------- readout: dot-first mean-pool + fused 512x10 GEMM epilogue -------
__global__ __launch_bounds__(512) void final_reduce(const float* __restrict__ x,
        const int* __restrict__ remap, const float* __restrict__ score,
        float* __restrict__ acc, const float* __restrict__ Wl,
        const float* __restrict__ bl, int* __restrict__ done,
        float* __restrict__ outp)
{
    __shared__ float gsh[512];
    __shared__ int last;
    int t = threadIdx.x; // 512
    int r0 = blockIdx.x * FR_RPB;
    float a = 0.f;
#pragma unroll
    for (int i = 0; i < FR_RPB; i += 4){
        int rr = r0 + i;
        float s0 = (remap[rr + 0] >= 0) ? score[rr + 0] : 0.f;
        float s1 = (remap[rr + 1] >= 0) ? score[rr + 1] : 0.f;
        float s2 = (remap[rr + 2] >= 0) ? score[rr + 2] : 0.f;
        float s3 = (remap[rr + 3] >= 0) ? score[rr + 3] : 0.f;
        float v0 = x[(size_t)(rr + 0) * FDIM + t];
        float v1 = x[(size_t)(rr + 1) * FDIM + t];
        float v2 = x[(size_t)(rr + 2) * FDIM + t];
        float v3 = x[(size_t)(rr + 3) * FDIM + t];
        a += v0 * s0 + v1 * s1 + v2 * s2 + v3 * s3;
    }
    gsh[t] = a;
    __syncthreads();
    int wv = t >> 6, lane = t & 63;
#pragma unroll
    for (int rep = 0; rep < 2; ++rep){
        int w = wv + rep * 8;
        if (w >= 10) break;
        float s = 0.f;
#pragma unroll
        for (int f = 0; f < 8; ++f) s += gsh[lane + f * 64] * Wl[(lane + f * 64) * 10 + w];
#pragma unroll
        for (int off = 32; off > 0; off >>= 1) s += __shfl_xor(s, off);
        if (lane == 0) atomicAdd(&acc[w * 32], s);
    }
    __syncthreads();
    if (t == 0){
        __threadfence();
        last = (atomicAdd(done, 1) == (int)gridDim.x - 1);
    }
    __syncthreads();
    if (!last) return;
    if (t < 10){
        float v = __hip_atomic_load(&acc[t * 32], __ATOMIC_RELAXED,
                                    __HIP_MEMORY_SCOPE_AGENT);
        outp[t] = v * (1.0f / K2_KEEP) + bl[t];
    }
}

extern "C" void kernel_launch(void* const* d_in, const int* in_sizes, int n_in,
                              void* d_out, int out_size, void* d_ws, size_t ws_size,
                              hipStream_t stream)
{
    (void)in_sizes; (void)n_in; (void)out_size; (void)ws_size;
    const float* x   = (const float*)d_in[0];
    const int*   ei  = (const int*)  d_in[1];
    const float* W1  = (const float*)d_in[3];
    const float* as1 = (const float*)d_in[4];
    const float* ad1 = (const float*)d_in[5];
    const float* b1  = (const float*)d_in[6];
    const float* pw1 = (const float*)d_in[7];
    const float* W2  = (const float*)d_in[8];
    const float* as2 = (const float*)d_in[9];
    const float* ad2 = (const float*)d_in[10];
    const float* b2  = (const float*)d_in[11];
    const float* pw2 = (const float*)d_in[12];
    const float* Wl  = (const float*)d_in[13];
    const float* bl  = (const float*)d_in[14];
    const int* src1 = ei;
    const int* dst1 = ei + E_EDGES;

    char* wsb = (char*)d_ws;
    size_t off = 0;
    auto alloc = [&](size_t bytes) -> char* {
        char* p = wsb + off;
        off += (bytes + 255) & ~(size_t)255;
        return p;
    };
    _Float16* h1f = (_Float16*)alloc((size_t)N_NODES * FDIM * 2); // fp16 gather rows (L1; L2 aliases)
    float* out1 = (float*)alloc((size_t)N_NODES * FDIM * 4);      // L1 GAT out; out2 aliases
    float* asrc = (float*)alloc((size_t)N_NODES * 8 * 4);         // half-pair dots [n][4][2]
    float* adst = (float*)alloc((size_t)N_NODES * 8 * 4);
    float* score= (float*)alloc((size_t)N_NODES * 4);
    float* invn = (float*)alloc(4);
    int* tmp  = (int*)alloc((size_t)N_NODES * 4);
    int* csr  = (int*)alloc((size_t)N_NODES * BSTRIDE * 4);
    int* remap= (int*)alloc((size_t)N_NODES * 4);
    float* racc = (float*)alloc(336 * 4);   // 10 line-padded accumulators + done@[320]
    unsigned* selbuf = (unsigned*)alloc(2 * SELWORDS * 4);      // select bins+meta (2 pools)
    _Float16* a0p = (_Float16*)alloc((size_t)MPAD * FDIM * 2);  // L2 A hi plane
    _Float16* a1p = (_Float16*)alloc((size_t)MPAD * FDIM * 2);  // L2 A lo plane
    _Float16* w2t0 = (_Float16*)alloc((size_t)FDIM * FDIM * 2); // W2^T hi
    _Float16* w2t1 = (_Float16*)alloc((size_t)FDIM * FDIM * 2); // W2^T lo
    _Float16* x0p = (_Float16*)alloc((size_t)MPAD1 * 64 * 2);   // L1 A hi plane
    _Float16* x1p = (_Float16*)alloc((size_t)MPAD1 * 64 * 2);   // L1 A lo plane
    _Float16* w1t0 = (_Float16*)alloc((size_t)FDIM * 64 * 2);   // W1^T hi
    _Float16* w1t1 = (_Float16*)alloc((size_t)FDIM * 64 * 2);   // W1^T lo
    _Float16* h2f = h1f;   // L2 gather rows alias L1's
    float* out2 = out1;    // L2 GAT out aliases out1
    int* done = (int*)(racc + 320);
    unsigned* sb1 = selbuf;                 // pool1: bA, bB(+4096), bC(+8192), meta(+8448)
    unsigned* sb2 = selbuf + SELWORDS;      // pool2

    // ---- layer 1 (GAT on N nodes, E edges + self loops), MFMA path ----
    prep_all<<<1063, 256, 0, stream>>>(x, x0p, x1p, W1, w1t0, w1t1,
            W2, w2t0, w2t1, tmp, N_NODES, pw1, invn, selbuf);
    gemm_mfma<64><<<(MPAD1 / 128) * 4, 256, 0, stream>>>(x0p, x1p, w1t0, w1t1,
            as1, ad1, h1f, asrc, adst, N_NODES);
    edge_fill<<<(E_EDGES + 255) / 256, 256, 0, stream>>>(src1, dst1, E_EDGES, tmp, csr);
    gat_fused<false><<<(N_NODES + 3) / 4, 256, 0, stream>>>(h1f, asrc, adst, tmp, csr,
            nullptr, b1, pw1, invn, out1, score, N_NODES);

    // ---- pool 1 (3-barrier multi-block select); also preps pw2-norm ----
    {
        int nb = (N_NODES + 511) / 512;   // 40 blocks, co-resident
        select3<<<nb, 256, 0, stream>>>(score, N_NODES, K1_KEEP, nb, remap,
                sb1, sb1 + 4096, sb1 + 8192, sb1 + 8448,
                nullptr, 0, pw2, invn);
    }

    // ---- layer 2: scatter-prep A (inverts remap), then fp16x2 MFMA GEMM ----
    {
        int nth = (N_NODES + (MPAD - K1_KEEP)) * 64;   // data + pad rows
        prep_a2<<<nth / 256, 256, 0, stream>>>(out1, remap, score, a0p, a1p);
    }
    gemm_mfma<512><<<(MPAD / 128) * 4, 256, 0, stream>>>(a0p, a1p, w2t0, w2t1,
            as2, ad2, h2f, asrc, adst, K1_KEEP);
    gat_fused<true><<<(N_NODES + 3) / 4, 256, 0, stream>>>(h2f, asrc, adst, tmp, csr,
            remap, b2, pw2, invn, out2, score, N_NODES);

    // ---- pool 2 (zeroes racc incl. done) + fused readout ----
    {
        int nb = (K1_KEEP + 511) / 512;   // 20 blocks
        select3<<<nb, 256, 0, stream>>>(score, K1_KEEP, K2_KEEP, nb, remap,
                sb2, sb2 + 4096, sb2 + 8192, sb2 + 8448,
                racc, 336, nullptr, nullptr);
    }
    final_reduce<<<FR_GRID, 512, 0, stream>>>(out2, remap, score, racc, Wl,
                                              bl, done, (float*)d_out);
}

// Round 19
// 264.139 us; speedup vs baseline: 1.0555x; 1.0555x over previous
//
#include <hip/hip_runtime.h>
#include <math.h>

#define N_NODES 20000
#define E_EDGES 200000
#define K1_KEEP 10000
#define K2_KEEP 5000
#define HIDC 128
#define NHEAD 4
#define FDIM 512   // NHEAD*HIDC
#define NEG 0.2f
#define BSTRIDE 64 // bucket CSR stride; P(deg>64)~e^-64 for Binom(200k,1/20k)
#define SELCAP 20  // keys/thread in select (1024*20 >= 20000)
#define MPAD 10112  // 79*128: K1 rows padded to GEMM2 tile grid
#define MPAD1 20096 // 157*128: N rows padded to GEMM1 tile grid
#define FR_GRID 250 // final_reduce blocks: 250*40 == K1_KEEP
#define FR_RPB 40   // rows per block (contiguous stream)

typedef _Float16 half8 __attribute__((ext_vector_type(8)));
typedef _Float16 half4 __attribute__((ext_vector_type(4)));
typedef float f32x4 __attribute__((ext_vector_type(4)));

__device__ __forceinline__ float leaky(float x){ return x > 0.f ? x : NEG * x; }
__device__ __forceinline__ float elu(float x){ return x > 0.f ? x : expm1f(x); }
// monotone float->uint key (ascending)
__device__ __forceinline__ unsigned ordkey(float f){
    unsigned u = __float_as_uint(f);
    return (u & 0x80000000u) ? ~u : (u | 0x80000000u);
}

// ---- prep_all: prep_x + W1 transpose-split + tmp zero + pw1-norm + prep_w2
__global__ __launch_bounds__(256) void prep_all(const float* __restrict__ x,
        _Float16* __restrict__ X0, _Float16* __restrict__ X1,
        const float* __restrict__ W1, _Float16* __restrict__ B10, _Float16* __restrict__ B11,
        const float* __restrict__ W2, _Float16* __restrict__ B20, _Float16* __restrict__ B21,
        int* __restrict__ ctmp, int cn,
        const float* __restrict__ cw, float* __restrict__ cinvn)
{
    int bid = blockIdx.x;
    int t = threadIdx.x;
    if (bid < 628){                       // --- prep_x: MPAD1*8 threads ---
        int tid = bid * 256 + t;
        int r = tid >> 3, c8 = (tid & 7) << 3;
        half8 v0 = (half8)0, v1 = (half8)0;
        if (r < N_NODES){
            const float4* p = reinterpret_cast<const float4*>(&x[(size_t)r * 64 + c8]);
            float4 x0 = p[0], x1 = p[1];
            float vals[8] = {x0.x, x0.y, x0.z, x0.w, x1.x, x1.y, x1.z, x1.w};
#pragma unroll
            for (int j = 0; j < 8; ++j){
                _Float16 h = (_Float16)vals[j];
                v0[j] = h;
                v1[j] = (_Float16)(vals[j] - (float)h);
            }
        }
        if (r < MPAD1){
            *reinterpret_cast<half8*>(&X0[(size_t)r * 64 + c8]) = v0;
            *reinterpret_cast<half8*>(&X1[(size_t)r * 64 + c8]) = v1;
        }
    } else if (bid < 660){                // --- W1[64][512] transpose-split ---
        __shared__ float tile[32][33];
        int b = bid - 628;
        int bn = b & 15, bk = b >> 4;
        int n0 = bn * 32, k0 = bk * 32;
        int j = t & 31, i0 = t >> 5;
#pragma unroll
        for (int ii = 0; ii < 32; ii += 8)
            tile[i0 + ii][j] = W1[(size_t)(k0 + i0 + ii) * 512 + n0 + j];
        __syncthreads();
#pragma unroll
        for (int ii = 0; ii < 32; ii += 8){
            float v = tile[j][i0 + ii];   // = W1[k0+j][n0+i0+ii]
            _Float16 h0 = (_Float16)v;
            _Float16 h1 = (_Float16)(v - (float)h0);
            size_t o = (size_t)(n0 + i0 + ii) * 64 + k0 + j;
            B10[o] = h0; B11[o] = h1;
        }
    } else if (bid < 739){                // --- tmp zero (degree counters) ---
        int i = (bid - 660) * 256 + t;
        if (i < cn) ctmp[i] = 0;
    } else if (bid == 739){               // --- 1/||pw1|| ---
        __shared__ float redc[4];
        float s = cw[t] * cw[t] + cw[t + 256] * cw[t + 256];
#pragma unroll
        for (int off = 32; off > 0; off >>= 1) s += __shfl_xor(s, off);
        if ((t & 63) == 0) redc[t >> 6] = s;
        __syncthreads();
        if (t == 0) *cinvn = rsqrtf(redc[0] + redc[1] + redc[2] + redc[3]);
    } else {                              // --- W2[512][512] transpose-split ---
        __shared__ float tile[32][33];
        int b = bid - 740;
        int bn = b & 15, bk = b >> 4;
        int n0 = bn * 32, k0 = bk * 32;
        int j = t & 31, i0 = t >> 5;
#pragma unroll
        for (int ii = 0; ii < 32; ii += 8)
            tile[i0 + ii][j] = W2[(size_t)(k0 + i0 + ii) * 512 + n0 + j];
        __syncthreads();
#pragma unroll
        for (int ii = 0; ii < 32; ii += 8){
            float v = tile[j][i0 + ii];   // = W2[k0+j][n0+i0+ii]
            _Float16 h0 = (_Float16)v;
            _Float16 h1 = (_Float16)(v - (float)h0);
            size_t o = (size_t)(n0 + i0 + ii) * 512 + k0 + j;
            B20[o] = h0; B21[o] = h1;
        }
    }
}

// --------- prep: scatter gather+scale+fp16x2-split A -> planes [MPAD][512] -
// r17: INVERTED (scatter) form — iterates ORIGINAL nodes o, writes row
// remap[o]; select no longer produces oldidx. Trailing blocks zero pad rows.
__global__ __launch_bounds__(256) void prep_a2(const float* __restrict__ out1,
        const int* __restrict__ remap, const float* __restrict__ score,
        _Float16* __restrict__ A0, _Float16* __restrict__ A1)
{
    int tid = blockIdx.x * 256 + threadIdx.x;   // N_NODES*64 + pad*64 total
    int o = tid >> 6, kq = (tid & 63) << 3;
    if (o < N_NODES){
        int r = remap[o];
        if (r < 0) return;
        float sc = score[o];
        const float4* p = reinterpret_cast<const float4*>(&out1[(size_t)o * 512 + kq]);
        float4 x0 = p[0], x1 = p[1];
        float vals[8] = {x0.x, x0.y, x0.z, x0.w, x1.x, x1.y, x1.z, x1.w};
        half8 v0, v1;
#pragma unroll
        for (int j = 0; j < 8; ++j){
            float v = vals[j] * sc;
            _Float16 h = (_Float16)v;
            v0[j] = h;
            v1[j] = (_Float16)(v - (float)h);
        }
        *reinterpret_cast<half8*>(&A0[(size_t)r * 512 + kq]) = v0;
        *reinterpret_cast<half8*>(&A1[(size_t)r * 512 + kq]) = v1;
    } else {
        int r = K1_KEEP + (o - N_NODES);        // pad rows K1..MPAD
        if (r < MPAD){
            *reinterpret_cast<half8*>(&A0[(size_t)r * 512 + kq]) = (half8)0;
            *reinterpret_cast<half8*>(&A1[(size_t)r * 512 + kq]) = (half8)0;
        }
    }
}

// ---------------- GEMM: fp16x2 split MFMA, 128x128 tile, templated K -------
template<int KK>
__global__ __launch_bounds__(256, 2) void gemm_mfma(
        const _Float16* __restrict__ A0, const _Float16* __restrict__ A1,
        const _Float16* __restrict__ B0, const _Float16* __restrict__ B1,
        const float* __restrict__ avS, const float* __restrict__ avD,
        _Float16* __restrict__ C, float* __restrict__ asrc, float* __restrict__ adst,
        int nrows)
{
    __shared__ _Float16 smem[2][4][128][32];   // 65536 B
    int t = threadIdx.x;
    int l = t & 63, w = t >> 6;
    int wr = w >> 1, wc = w & 1;
    int bidn = blockIdx.x & 3, bidm = blockIdx.x >> 2;
    int row0 = bidm * 128, col0 = bidn * 128;

    const _Float16* plane = (w == 0) ? A0 : (w == 1) ? A1 : (w == 2) ? B0 : B1;
    int prow0 = (w < 2) ? row0 : col0;
    int mloc = l >> 2;
    int gsw = (l & 3) ^ (mloc & 3);
    const _Float16* gbase = plane + (size_t)(prow0 + mloc) * KK + gsw * 8;

    f32x4 acc[4][4];
#pragma unroll
    for (int m = 0; m < 4; ++m)
#pragma unroll
        for (int n = 0; n < 4; ++n) acc[m][n] = (f32x4){0.f, 0.f, 0.f, 0.f};

    auto stage = [&](int buf, int chunk){
        const _Float16* src = gbase + chunk * 32;
        char* db = (char*)&smem[buf][w][0][0];
#pragma unroll
        for (int i = 0; i < 8; ++i)
            __builtin_amdgcn_global_load_lds(
                (const __attribute__((address_space(1))) void*)(src + (size_t)i * (KK * 16)),
                (__attribute__((address_space(3))) void*)(db + i * 1024), 16, 0, 0);
    };

    int rb = (l & 15) * 64 + (((l >> 4) ^ (l & 3)) * 16);
    const char* sb = (const char*)smem;

    constexpr int NCH = KK / 32;
    stage(0, 0);
    __syncthreads();
    for (int c = 0; c < NCH; ++c){
        int buf = c & 1;
        if (c < NCH - 1) stage(buf ^ 1, c + 1);
        const char* base = sb + buf * 32768;
        half8 a0[4], a1[4], b0[4], b1[4];
#pragma unroll
        for (int m = 0; m < 4; ++m){
            a0[m] = *(const half8*)(base +         wr * 4096 + m * 1024 + rb);
            a1[m] = *(const half8*)(base +  8192 + wr * 4096 + m * 1024 + rb);
            b0[m] = *(const half8*)(base + 16384 + wc * 4096 + m * 1024 + rb);
            b1[m] = *(const half8*)(base + 24576 + wc * 4096 + m * 1024 + rb);
        }
#pragma unroll
        for (int m = 0; m < 4; ++m)
#pragma unroll
            for (int n = 0; n < 4; ++n)
                acc[m][n] = __builtin_amdgcn_mfma_f32_16x16x32_f16(a0[m], b0[n], acc[m][n], 0, 0, 0);
#pragma unroll
        for (int m = 0; m < 4; ++m)
#pragma unroll
            for (int n = 0; n < 4; ++n)
                acc[m][n] = __builtin_amdgcn_mfma_f32_16x16x32_f16(a0[m], b1[n], acc[m][n], 0, 0, 0);
#pragma unroll
        for (int m = 0; m < 4; ++m)
#pragma unroll
            for (int n = 0; n < 4; ++n)
                acc[m][n] = __builtin_amdgcn_mfma_f32_16x16x32_f16(a1[m], b0[n], acc[m][n], 0, 0, 0);
        __syncthreads();
    }

    int head = bidn;
    const float* asv = avS + head * HIDC + wc * 64;
    const float* adv = avD + head * HIDC + wc * 64;
    int lc = l & 15, lg = l >> 4;
    int rbase = row0 + wr * 64;
    int cbase = col0 + wc * 64;
#pragma unroll
    for (int m = 0; m < 4; ++m){
#pragma unroll
        for (int q = 0; q < 4; ++q){
            int row = rbase + m * 16 + lg * 4 + q;
            bool ok = row < nrows;
            float s = 0.f, d = 0.f;
#pragma unroll
            for (int n = 0; n < 4; ++n){
                float v = acc[m][n][q];
                int cc = n * 16 + lc;
                if (ok) C[(size_t)row * 512 + cbase + cc] = (_Float16)v;
                s += v * asv[cc];
                d += v * adv[cc];
            }
#pragma unroll
            for (int off = 1; off < 16; off <<= 1){
                s += __shfl_xor(s, off);
                d += __shfl_xor(d, off);
            }
            if (ok && lc == 0){
                asrc[row * 8 + head * 2 + wc] = s;
                adst[row * 8 + head * 2 + wc] = d;
            }
        }
    }
}

// bucketed CSR fill
__global__ void edge_fill(const int* __restrict__ src, const int* __restrict__ dst, int e,
                          int* __restrict__ tmp, int* __restrict__ csr){
    int i = blockIdx.x * 256 + threadIdx.x;
    if (i >= e) return;
    int d = dst[i];
    int pos = atomicAdd(&tmp[d], 1);
    if (pos < BSTRIDE) csr[d * BSTRIDE + pos] = src[i];
}

// ---- fused softmax-stats + aggregation + pool score, one wave per node -----
// r17 (FILTER=true): iterates ORIGINAL node ids o; node = remap[o], od = o.
template<bool FILTER>
__global__ __launch_bounds__(256) void gat_fused(const _Float16* __restrict__ h,
        const float* __restrict__ asrc, const float* __restrict__ adst,
        const int* __restrict__ degs, const int* __restrict__ csr,
        const int* __restrict__ remap,
        const float* __restrict__ bias, const float* __restrict__ pw,
        const float* __restrict__ invn, float* __restrict__ out,
        float* __restrict__ score, int n)
{
    int o = blockIdx.x * 4 + (threadIdx.x >> 6);
    int lane = threadIdx.x & 63;
    if (o >= n) return;
    int node, od;
    if (FILTER){
        node = remap[o];
        if (node < 0) return;
        od = o;
    } else {
        node = o; od = o;
    }
    int deg = degs[od]; if (deg > BSTRIDE) deg = BSTRIDE;
    int e0 = od * BSTRIDE;
    int ph = lane & 3;
    int pe = lane >> 2;
    float adn, sown;
    {
        float2 dv = *reinterpret_cast<const float2*>(&adst[(size_t)node * 8 + ph * 2]);
        float2 sv = *reinterpret_cast<const float2*>(&asrc[(size_t)node * 8 + ph * 2]);
        adn = dv.x + dv.y; sown = sv.x + sv.y;
    }
    float slog = leaky(sown + adn);
    int sreg[4];
    float mx = slog;
#pragma unroll
    for (int blk = 0; blk < 4; ++blk){
        int j = blk * 16 + pe;
        int s = -1;
        if (j < deg){
            s = csr[e0 + j];
            if (FILTER) s = remap[s];
            if (s >= 0){
                float2 v = *reinterpret_cast<const float2*>(&asrc[(size_t)s * 8 + ph * 2]);
                mx = fmaxf(mx, leaky(v.x + v.y + adn));
            }
        }
        sreg[blk] = s;
    }
#pragma unroll
    for (int off = 4; off < 64; off <<= 1) mx = fmaxf(mx, __shfl_xor(mx, off));
    float aexp[4];
    float lsum = 0.f;
#pragma unroll
    for (int blk = 0; blk < 4; ++blk){
        float ex = 0.f;
        int s = sreg[blk];
        if (s >= 0){
            float2 v = *reinterpret_cast<const float2*>(&asrc[(size_t)s * 8 + ph * 2]);
            ex = expf(leaky(v.x + v.y + adn) - mx);
        }
        aexp[blk] = ex;
        lsum += ex;
    }
#pragma unroll
    for (int off = 4; off < 64; off <<= 1) lsum += __shfl_xor(lsum, off);
    float es  = expf(slog - mx);
    float inv = 1.f / (lsum + es);

    int f0 = lane * 8;
    int hf = lane >> 4;
    float invh  = __shfl(inv, hf);
    float aself = __shfl(es, hf) * invh;
    float4 acc0, acc1;
    {
        half8 v = *reinterpret_cast<const half8*>(&h[(size_t)node * FDIM + f0]);
        acc0 = make_float4(aself * (float)v[0], aself * (float)v[1],
                           aself * (float)v[2], aself * (float)v[3]);
        acc1 = make_float4(aself * (float)v[4], aself * (float)v[5],
                           aself * (float)v[6], aself * (float)v[7]);
    }
#pragma unroll
    for (int blk = 0; blk < 4; ++blk){
        int base = blk * 16;
        if (base >= deg) break;
        int cnt = deg - base; if (cnt > 16) cnt = 16;
        for (int e = 0; e < cnt; ++e){
            int s = __shfl(sreg[blk], e * 4);
            if (FILTER && s < 0) continue;
            float al = __shfl(aexp[blk], e * 4 + hf) * invh;
            half8 u = *reinterpret_cast<const half8*>(&h[(size_t)s * FDIM + f0]);
            acc0.x += al * (float)u[0]; acc0.y += al * (float)u[1];
            acc0.z += al * (float)u[2]; acc0.w += al * (float)u[3];
            acc1.x += al * (float)u[4]; acc1.y += al * (float)u[5];
            acc1.z += al * (float)u[6]; acc1.w += al * (float)u[7];
        }
    }
    const float4* bp = reinterpret_cast<const float4*>(&bias[f0]);
    float4 b0 = bp[0], b1 = bp[1];
    float4 o0 = make_float4(elu(acc0.x + b0.x), elu(acc0.y + b0.y),
                            elu(acc0.z + b0.z), elu(acc0.w + b0.w));
    float4 o1 = make_float4(elu(acc1.x + b1.x), elu(acc1.y + b1.y),
                            elu(acc1.z + b1.z), elu(acc1.w + b1.w));
    float4* op = reinterpret_cast<float4*>(&out[(size_t)node * FDIM + f0]);
    op[0] = o0; op[1] = o1;
    const float4* wp = reinterpret_cast<const float4*>(&pw[f0]);
    float4 w0 = wp[0], w1 = wp[1];
    float s = o0.x * w0.x + o0.y * w0.y + o0.z * w0.z + o0.w * w0.w
            + o1.x * w1.x + o1.y * w1.y + o1.z * w1.z + o1.w * w1.w;
#pragma unroll
    for (int off = 32; off > 0; off >>= 1) s += __shfl_xor(s, off);
    if (lane == 0) score[node] = tanhf(s * (*invn));
}

// ---- exact top-k select: 12/12/8-bit radix + scan-compact, single block ----
// Final form: the ~50us/select is the global-coordination latency floor of
// exact data-dependent top-k (1-block monolith cheapest; multi-launch r13,
// 8-barrier r14, 3-barrier r18 all equal or worse). remap-only output.
__global__ __launch_bounds__(1024) void select_compact(const float* __restrict__ score,
        int n, int k, int* __restrict__ remap,
        float* __restrict__ zbuf, int zn,
        const float* __restrict__ w, float* __restrict__ invn)
{
    __shared__ unsigned hist[4][4096];     // 64 KB; copy per 4-wave group
    __shared__ unsigned wsum[16];
    __shared__ unsigned s_prefix, s_rem;
    __shared__ float red2[16];
    int t = threadIdx.x;
    int wv = t >> 6;
    int lane = t & 63;
    int hc = wv >> 2;
    unsigned keys[SELCAP];
#pragma unroll
    for (int j = 0; j < SELCAP; ++j){
        int i = t + j * 1024;
        keys[j] = (i < n) ? ordkey(score[i]) : 0u;
    }
    if (t == 0){ s_prefix = 0u; s_rem = (unsigned)k; }
    for (int i = t; i < 4 * 4096; i += 1024) ((unsigned*)hist)[i] = 0u;
    if (zbuf && t < zn) zbuf[t] = 0.f;
    __syncthreads();

    // ---- pass A: bits[31:20] ----
#pragma unroll
    for (int j = 0; j < SELCAP; ++j){
        int i = t + j * 1024;
        if (i < n) atomicAdd(&hist[hc][keys[j] >> 20], 1u);
    }
    __syncthreads();
    {
        unsigned rem = s_rem;              // == k; read before any write
        unsigned c[4]; unsigned sown = 0;
#pragma unroll
        for (int b = 0; b < 4; ++b){
            int bin = t * 4 + b;
            c[b] = hist[0][bin] + hist[1][bin] + hist[2][bin] + hist[3][bin];
            sown += c[b];
        }
        unsigned v = sown;
#pragma unroll
        for (int off = 1; off < 64; off <<= 1){
            unsigned o = __shfl_down(v, off);
            if (lane + off < 64) v += o;
        }
        if (lane == 0) wsum[wv] = v;
        __syncthreads();
        unsigned hi = 0;
        for (int q = wv + 1; q < 16; ++q) hi += wsum[q];
        unsigned run = v + hi - sown;      // suffix starting at thread t+1
#pragma unroll
        for (int b = 3; b >= 0; --b){
            unsigned suf = run + c[b];
            if (suf >= rem && run < rem){
                s_prefix = (unsigned)(t * 4 + b) << 20;
                s_rem = rem - run;
            }
            run = suf;
        }
    }
    __syncthreads();
    unsigned prefA = s_prefix;
    for (int i = t; i < 4 * 4096; i += 1024) ((unsigned*)hist)[i] = 0u;
    __syncthreads();

    // ---- pass B: bits[19:8] among keys matching 12-bit prefix ----
#pragma unroll
    for (int j = 0; j < SELCAP; ++j){
        int i = t + j * 1024;
        if (i < n && (keys[j] >> 20) == (prefA >> 20))
            atomicAdd(&hist[hc][(keys[j] >> 8) & 0xFFFu], 1u);
    }
    __syncthreads();
    {
        unsigned rem = s_rem;
        unsigned c[4]; unsigned sown = 0;
#pragma unroll
        for (int b = 0; b < 4; ++b){
            int bin = t * 4 + b;
            c[b] = hist[0][bin] + hist[1][bin] + hist[2][bin] + hist[3][bin];
            sown += c[b];
        }
        unsigned v = sown;
#pragma unroll
        for (int off = 1; off < 64; off <<= 1){
            unsigned o = __shfl_down(v, off);
            if (lane + off < 64) v += o;
        }
        if (lane == 0) wsum[wv] = v;
        __syncthreads();
        unsigned hi = 0;
        for (int q = wv + 1; q < 16; ++q) hi += wsum[q];
        unsigned run = v + hi - sown;
#pragma unroll
        for (int b = 3; b >= 0; --b){
            unsigned suf = run + c[b];
            if (suf >= rem && run < rem){
                s_prefix = prefA | ((unsigned)(t * 4 + b) << 8);
                s_rem = rem - run;
            }
            run = suf;
        }
    }
    __syncthreads();
    unsigned prefB = s_prefix;
    for (int i = t; i < 4 * 4096; i += 1024) ((unsigned*)hist)[i] = 0u;
    __syncthreads();

    // ---- pass C: bits[7:0] among keys matching 24-bit prefix ----
#pragma unroll
    for (int j = 0; j < SELCAP; ++j){
        int i = t + j * 1024;
        if (i < n && (keys[j] >> 8) == (prefB >> 8))
            atomicAdd(&hist[hc][keys[j] & 255u], 1u);
    }
    __syncthreads();
    {
        unsigned rem = s_rem;
        unsigned cC = 0, vC = 0;
        if (t < 256){
            cC = hist[0][t] + hist[1][t] + hist[2][t] + hist[3][t];
            vC = cC;
#pragma unroll
            for (int off = 1; off < 64; off <<= 1){
                unsigned o = __shfl_down(vC, off);
                if ((t & 63) + off < 64) vC += o;
            }
            if ((t & 63) == 0) wsum[t >> 6] = vC;
        }
        __syncthreads();
        if (t < 256){
#pragma unroll
            for (int q = 0; q < 4; ++q)
                if (q > (t >> 6)) vC += wsum[q];
            unsigned nxt = vC - cC;
            if (vC >= rem && nxt < rem){
                s_prefix = prefB | (unsigned)t;
                s_rem = rem - nxt;
            }
        }
    }
    __syncthreads();

    unsigned T = s_prefix, ties = s_rem;
    // --- scan-based compaction: remap only (coalesced writes) ---
    int ngt = 0, ntie = 0;
#pragma unroll
    for (int j = 0; j < SELCAP; ++j){
        int i = t + j * 1024;
        if (i >= n) continue;
        if (keys[j] > T) ++ngt;
        else if (keys[j] == T) ++ntie;
    }
    unsigned pk = ((unsigned)ngt << 16) | (unsigned)ntie;
    unsigned v2 = pk;
#pragma unroll
    for (int off = 1; off < 64; off <<= 1){
        unsigned o = __shfl_up(v2, off);
        if (lane >= off) v2 += o;
    }
    if (lane == 63) wsum[wv] = v2;
    __syncthreads();
    unsigned base = 0;
    for (int q = 0; q < wv; ++q) base += wsum[q];
    unsigned excl = base + v2 - pk;            // exclusive prefix for this thread
    int gpos = (int)(excl >> 16);
    int tpos = (int)(excl & 0xFFFFu);
    int gtot = k - (int)ties;                  // radix invariant: #(key>T) == k-ties
#pragma unroll
    for (int j = 0; j < SELCAP; ++j){
        int i = t + j * 1024;
        if (i >= n) continue;
        unsigned key = keys[j];
        int pos = -1;
        if (key > T) pos = gpos++;
        else if (key == T){
            int tr = tpos++;
            if (tr < (int)ties) pos = gtot + tr;
        }
        remap[i] = pos;
    }
    if (w){
        float s = (t < 512) ? w[t] * w[t] : 0.f;
#pragma unroll
        for (int off = 32; off > 0; off >>= 1) s += __shfl_xor(s, off);
        if ((t & 63) == 0) red2[wv] = s;
        __syncthreads();
        if (t == 0){
            float a = 0.f;
            for (int i = 0; i < 16; ++i) a += red2[i];
            *invn = rsqrtf(a);
        }
    }
}

// --------- readout: dot-first mean-pool + fused 512x10 GEMM epilogue -------
__global__ __launch_bounds__(512) void final_reduce(const float* __restrict__ x,
        const int* __restrict__ remap, const float* __restrict__ score,
        float* __restrict__ acc, const float* __restrict__ Wl,
        const float* __restrict__ bl, int* __restrict__ done,
        float* __restrict__ outp)
{
    __shared__ float gsh[512];
    __shared__ int last;
    int t = threadIdx.x; // 512
    int r0 = blockIdx.x * FR_RPB;
    float a = 0.f;
#pragma unroll
    for (int i = 0; i < FR_RPB; i += 4){
        int rr = r0 + i;
        float s0 = (remap[rr + 0] >= 0) ? score[rr + 0] : 0.f;
        float s1 = (remap[rr + 1] >= 0) ? score[rr + 1] : 0.f;
        float s2 = (remap[rr + 2] >= 0) ? score[rr + 2] : 0.f;
        float s3 = (remap[rr + 3] >= 0) ? score[rr + 3] : 0.f;
        float v0 = x[(size_t)(rr + 0) * FDIM + t];
        float v1 = x[(size_t)(rr + 1) * FDIM + t];
        float v2 = x[(size_t)(rr + 2) * FDIM + t];
        float v3 = x[(size_t)(rr + 3) * FDIM + t];
        a += v0 * s0 + v1 * s1 + v2 * s2 + v3 * s3;
    }
    gsh[t] = a;
    __syncthreads();
    int wv = t >> 6, lane = t & 63;
#pragma unroll
    for (int rep = 0; rep < 2; ++rep){
        int w = wv + rep * 8;
        if (w >= 10) break;
        float s = 0.f;
#pragma unroll
        for (int f = 0; f < 8; ++f) s += gsh[lane + f * 64] * Wl[(lane + f * 64) * 10 + w];
#pragma unroll
        for (int off = 32; off > 0; off >>= 1) s += __shfl_xor(s, off);
        if (lane == 0) atomicAdd(&acc[w * 32], s);
    }
    __syncthreads();
    if (t == 0){
        __threadfence();
        last = (atomicAdd(done, 1) == (int)gridDim.x - 1);
    }
    __syncthreads();
    if (!last) return;
    if (t < 10){
        float v = __hip_atomic_load(&acc[t * 32], __ATOMIC_RELAXED,
                                    __HIP_MEMORY_SCOPE_AGENT);
        outp[t] = v * (1.0f / K2_KEEP) + bl[t];
    }
}

extern "C" void kernel_launch(void* const* d_in, const int* in_sizes, int n_in,
                              void* d_out, int out_size, void* d_ws, size_t ws_size,
                              hipStream_t stream)
{
    (void)in_sizes; (void)n_in; (void)out_size; (void)ws_size;
    const float* x   = (const float*)d_in[0];
    const int*   ei  = (const int*)  d_in[1];
    const float* W1  = (const float*)d_in[3];
    const float* as1 = (const float*)d_in[4];
    const float* ad1 = (const float*)d_in[5];
    const float* b1  = (const float*)d_in[6];
    const float* pw1 = (const float*)d_in[7];
    const float* W2  = (const float*)d_in[8];
    const float* as2 = (const float*)d_in[9];
    const float* ad2 = (const float*)d_in[10];
    const float* b2  = (const float*)d_in[11];
    const float* pw2 = (const float*)d_in[12];
    const float* Wl  = (const float*)d_in[13];
    const float* bl  = (const float*)d_in[14];
    const int* src1 = ei;
    const int* dst1 = ei + E_EDGES;

    char* wsb = (char*)d_ws;
    size_t off = 0;
    auto alloc = [&](size_t bytes) -> char* {
        char* p = wsb + off;
        off += (bytes + 255) & ~(size_t)255;
        return p;
    };
    _Float16* h1f = (_Float16*)alloc((size_t)N_NODES * FDIM * 2); // fp16 gather rows (L1; L2 aliases)
    float* out1 = (float*)alloc((size_t)N_NODES * FDIM * 4);      // L1 GAT out; out2 aliases
    float* asrc = (float*)alloc((size_t)N_NODES * 8 * 4);         // half-pair dots [n][4][2]
    float* adst = (float*)alloc((size_t)N_NODES * 8 * 4);
    float* score= (float*)alloc((size_t)N_NODES * 4);
    float* invn = (float*)alloc(4);
    int* tmp  = (int*)alloc((size_t)N_NODES * 4);
    int* csr  = (int*)alloc((size_t)N_NODES * BSTRIDE * 4);
    int* remap= (int*)alloc((size_t)N_NODES * 4);
    float* racc = (float*)alloc(336 * 4);   // 10 line-padded accumulators + done@[320]
    _Float16* a0p = (_Float16*)alloc((size_t)MPAD * FDIM * 2);  // L2 A hi plane
    _Float16* a1p = (_Float16*)alloc((size_t)MPAD * FDIM * 2);  // L2 A lo plane
    _Float16* w2t0 = (_Float16*)alloc((size_t)FDIM * FDIM * 2); // W2^T hi
    _Float16* w2t1 = (_Float16*)alloc((size_t)FDIM * FDIM * 2); // W2^T lo
    _Float16* x0p = (_Float16*)alloc((size_t)MPAD1 * 64 * 2);   // L1 A hi plane
    _Float16* x1p = (_Float16*)alloc((size_t)MPAD1 * 64 * 2);   // L1 A lo plane
    _Float16* w1t0 = (_Float16*)alloc((size_t)FDIM * 64 * 2);   // W1^T hi
    _Float16* w1t1 = (_Float16*)alloc((size_t)FDIM * 64 * 2);   // W1^T lo
    _Float16* h2f = h1f;   // L2 gather rows alias L1's
    float* out2 = out1;    // L2 GAT out aliases out1
    int* done = (int*)(racc + 320);

    // ---- layer 1 (GAT on N nodes, E edges + self loops), MFMA path ----
    prep_all<<<996, 256, 0, stream>>>(x, x0p, x1p, W1, w1t0, w1t1,
            W2, w2t0, w2t1, tmp, N_NODES, pw1, invn);
    gemm_mfma<64><<<(MPAD1 / 128) * 4, 256, 0, stream>>>(x0p, x1p, w1t0, w1t1,
            as1, ad1, h1f, asrc, adst, N_NODES);
    edge_fill<<<(E_EDGES + 255) / 256, 256, 0, stream>>>(src1, dst1, E_EDGES, tmp, csr);
    gat_fused<false><<<(N_NODES + 3) / 4, 256, 0, stream>>>(h1f, asrc, adst, tmp, csr,
            nullptr, b1, pw1, invn, out1, score, N_NODES);

    // ---- pool 1 (remap only; no oldidx); also preps pw2-norm ----
    select_compact<<<1, 1024, 0, stream>>>(score, N_NODES, K1_KEEP, remap,
                                           nullptr, 0, pw2, invn);

    // ---- layer 2: scatter-prep A (inverts remap), then fp16x2 MFMA GEMM ----
    {
        int nth = (N_NODES + (MPAD - K1_KEEP)) * 64;   // data + pad rows
        prep_a2<<<nth / 256, 256, 0, stream>>>(out1, remap, score, a0p, a1p);
    }
    gemm_mfma<512><<<(MPAD / 128) * 4, 256, 0, stream>>>(a0p, a1p, w2t0, w2t1,
            as2, ad2, h2f, asrc, adst, K1_KEEP);
    gat_fused<true><<<(N_NODES + 3) / 4, 256, 0, stream>>>(h2f, asrc, adst, tmp, csr,
            remap, b2, pw2, invn, out2, score, N_NODES);

    // ---- pool 2 (zeroes racc incl. done) + fused readout ----
    select_compact<<<1, 1024, 0, stream>>>(score, K1_KEEP, K2_KEEP, remap,
                                           racc, 336, nullptr, nullptr);
    final_reduce<<<FR_GRID, 512, 0, stream>>>(out2, remap, score, racc, Wl,
                                              bl, done, (float*)d_out);
}